// Round 5
// baseline (5260.516 us; speedup 1.0000x reference)
//
#include <hip/hip_runtime.h>
#include <hip/hip_bf16.h>

#define NB 64
#define TT 1024
#define ND 512
#define NH 1024
#define GRID 256
#define NTH 256

typedef float f32x4 __attribute__((ext_vector_type(4)));
typedef unsigned u32x4 __attribute__((ext_vector_type(4)));
typedef __bf16 bf16x8 __attribute__((ext_vector_type(8)));

__device__ __forceinline__ float sigmoid_f(float v) { return 1.0f / (1.0f + __expf(-v)); }

__device__ __forceinline__ float tanh_f(float v) {
    float a = fabsf(v);
    float e = __expf(-2.0f * a);
    float t = (1.0f - e) / (1.0f + e);
    return copysignf(t, v);
}

// ---- device-scope (MALL-coherent, cache-bypassing) accessors: sc1 ----
__device__ __forceinline__ u32x4 load_dwordx4_sc1_off(const unsigned* p, int imm) {
    u32x4 r;
    asm volatile("global_load_dwordx4 %0, %1, off offset:%2 sc1"
                 : "=v"(r) : "v"(p), "i"(imm));
    return r;
}
__device__ __forceinline__ void store_dword_sc1(unsigned* p, unsigned v) {
    asm volatile("global_store_dword %0, %1, off sc1" :: "v"(p), "v"(v) : "memory");
}
__device__ __forceinline__ unsigned load_dword_sc1_wait(const unsigned* p) {
    unsigned v;
    asm volatile("global_load_dword %0, %1, off sc1\n\ts_waitcnt vmcnt(0)"
                 : "=v"(v) : "v"(p) : "memory");
    return v;
}

// LDS weights in exact MFMA B-fragment order: every read is a lane-contiguous
// 1KB ds_read_b128 (conflict-free).
// h state: 2 parity buffers of 32-bit words, word = (tag<<16)|bf16(h).
// A dword store is atomic, so the data carries its own readiness flag:
// producer never drains/flags; consumer sees valid data one RT after arrival.
__global__ void __launch_bounds__(NTH) gru_kernel(
    const float* __restrict__ x, const float* __restrict__ W_ih,
    const float* __restrict__ W_hh, const float* __restrict__ b_ih,
    const float* __restrict__ b_hh, float* __restrict__ out,
    unsigned* __restrict__ hbuf)
{
    extern __shared__ char smem[];
    __bf16* WihF = (__bf16*)smem;                  // 49152 B
    __bf16* WhhF = WihF + 4 * 4 * 3 * 64 * 8;      // 98304 B
    float* prz = (float*)(WhhF + 4 * 8 * 3 * 64 * 8);  // [4][16][32] = 8192 B
    float* pnx = prz + 2048;                       // [4][16][16] = 4096 B
    float* pnh = pnx + 1024;                       // [4][16][16] = 4096 B
    // total 163840 B

    const int tid = threadIdx.x;
    const int bg = blockIdx.x >> 6;   // batch group — independent sync group
    const int cg = blockIdx.x & 63;   // hidden-col group
    const int brow = bg << 4;
    const int hc0 = cg << 4;

    // ---- one-time: fill fragment-ordered weight LDS (fp32 -> bf16) ----
    for (int s = tid; s < 4 * 4 * 3 * 64; s += NTH) {      // W_ih slots
        int ln = s & 63, r = s >> 6;
        int g = r % 3, r2 = r / 3;
        int it = r2 & 3, w = r2 >> 2;
        int k = w * 128 + it * 32 + (ln >> 4) * 8;
        int col = ln & 15;
        const float* src = W_ih + (size_t)(g * NH + hc0 + col) * ND + k;
        float4 va = *(const float4*)(src);
        float4 vb = *(const float4*)(src + 4);
        bf16x8 f;
        f[0] = (__bf16)va.x; f[1] = (__bf16)va.y; f[2] = (__bf16)va.z; f[3] = (__bf16)va.w;
        f[4] = (__bf16)vb.x; f[5] = (__bf16)vb.y; f[6] = (__bf16)vb.z; f[7] = (__bf16)vb.w;
        *(bf16x8*)(WihF + (size_t)s * 8) = f;
    }
    for (int s = tid; s < 4 * 8 * 3 * 64; s += NTH) {      // W_hh slots
        int ln = s & 63, r = s >> 6;
        int g = r % 3, r2 = r / 3;
        int it = r2 & 7, w = r2 >> 3;
        int k = w * 256 + it * 32 + (ln >> 4) * 8;
        int col = ln & 15;
        const float* src = W_hh + (size_t)(g * NH + hc0 + col) * NH + k;
        float4 va = *(const float4*)(src);
        float4 vb = *(const float4*)(src + 4);
        bf16x8 f;
        f[0] = (__bf16)va.x; f[1] = (__bf16)va.y; f[2] = (__bf16)va.z; f[3] = (__bf16)va.w;
        f[4] = (__bf16)vb.x; f[5] = (__bf16)vb.y; f[6] = (__bf16)vb.z; f[7] = (__bf16)vb.w;
        *(bf16x8*)(WhhF + (size_t)s * 8) = f;
    }

    const int jcol = tid & 15;
    const int mrow = tid >> 4;
    const float b_r = b_ih[hc0 + jcol] + b_hh[hc0 + jcol];
    const float b_z = b_ih[NH + hc0 + jcol] + b_hh[NH + hc0 + jcol];
    const float b_nx = b_ih[2 * NH + hc0 + jcol];
    const float b_nh = b_hh[2 * NH + hc0 + jcol];

    __syncthreads();

    const int wave = tid >> 6;
    const int lane = tid & 63;
    const int lrow = lane & 15;
    const int kgrp = lane >> 4;

    // consumer h base (word units)
    const size_t hoff_c = (size_t)(brow + lrow) * NH + wave * 256 + kgrp * 8;
    // canary: one word per producer-wave granule (4 rows x 16 cols). lane ->
    // producer block b = lane>>2 (k = wave*256+b*16), producer wave pw = lane&3.
    const size_t hoff_cn = (size_t)(brow + 4 * (lane & 3)) * NH + wave * 256 + (lane >> 2) * 16;
    // producer store offset (gate-math role)
    const size_t hoff_p = (size_t)(brow + mrow) * NH + hc0 + jcol;

    float hp = 0.0f;   // fp32 hidden-state carry in a register

    // prologue: prefetch x fragment for t=0
    f32x4 xa[4], xb[4];
    {
        const float* xr = x + ((size_t)(brow + lrow) * TT + 0) * ND + wave * 128 + kgrp * 8;
        #pragma unroll
        for (int it = 0; it < 4; ++it) {
            xa[it] = *(const f32x4*)(xr + it * 32);
            xb[it] = *(const f32x4*)(xr + it * 32 + 4);
        }
    }

    for (int t = 0; t < TT; ++t) {
        const int par = t & 1;
        f32x4 ar{}, az{}, anx{}, anh{};

        // ---- x-part from prefetched registers ----
        #pragma unroll
        for (int it = 0; it < 4; ++it) {
            bf16x8 af;
            af[0] = (__bf16)xa[it][0]; af[1] = (__bf16)xa[it][1];
            af[2] = (__bf16)xa[it][2]; af[3] = (__bf16)xa[it][3];
            af[4] = (__bf16)xb[it][0]; af[5] = (__bf16)xb[it][1];
            af[6] = (__bf16)xb[it][2]; af[7] = (__bf16)xb[it][3];
            const __bf16* wp = WihF + ((size_t)(wave * 4 + it) * 3) * 512 + lane * 8;
            bf16x8 wr = *(const bf16x8*)(wp);
            bf16x8 wz = *(const bf16x8*)(wp + 512);
            bf16x8 wn = *(const bf16x8*)(wp + 1024);
            ar  = __builtin_amdgcn_mfma_f32_16x16x32_bf16(af, wr, ar, 0, 0, 0);
            az  = __builtin_amdgcn_mfma_f32_16x16x32_bf16(af, wz, az, 0, 0, 0);
            anx = __builtin_amdgcn_mfma_f32_16x16x32_bf16(af, wn, anx, 0, 0, 0);
        }

        // ---- prefetch x(t+1) early: latency hides under the h poll ----
        if (t + 1 < TT) {
            const float* xn = x + ((size_t)(brow + lrow) * TT + (t + 1)) * ND
                            + wave * 128 + kgrp * 8;
            #pragma unroll
            for (int it = 0; it < 4; ++it) {
                xa[it] = *(const f32x4*)(xn + it * 32);
                xb[it] = *(const f32x4*)(xn + it * 32 + 4);
            }
        }

        // ---- self-validating h load: data + embedded tag, one RT ----
        const unsigned tag = (unsigned)t;
        const unsigned* hbase = hbuf + (size_t)par * NB * NH + hoff_c;
        const unsigned* cbase = hbuf + (size_t)par * NB * NH + hoff_cn;
        u32x4 hw[16];
        for (;;) {
            hw[0]  = load_dwordx4_sc1_off(hbase,   0); hw[1]  = load_dwordx4_sc1_off(hbase,  16);
            hw[2]  = load_dwordx4_sc1_off(hbase, 128); hw[3]  = load_dwordx4_sc1_off(hbase, 144);
            hw[4]  = load_dwordx4_sc1_off(hbase, 256); hw[5]  = load_dwordx4_sc1_off(hbase, 272);
            hw[6]  = load_dwordx4_sc1_off(hbase, 384); hw[7]  = load_dwordx4_sc1_off(hbase, 400);
            hw[8]  = load_dwordx4_sc1_off(hbase, 512); hw[9]  = load_dwordx4_sc1_off(hbase, 528);
            hw[10] = load_dwordx4_sc1_off(hbase, 640); hw[11] = load_dwordx4_sc1_off(hbase, 656);
            hw[12] = load_dwordx4_sc1_off(hbase, 768); hw[13] = load_dwordx4_sc1_off(hbase, 784);
            hw[14] = load_dwordx4_sc1_off(hbase, 896); hw[15] = load_dwordx4_sc1_off(hbase, 912);
            asm volatile("s_waitcnt vmcnt(0)" ::: "memory");
            __builtin_amdgcn_sched_barrier(0);
            unsigned acc = 0;
            #pragma unroll
            for (int i = 0; i < 16; ++i) {
                acc |= ((hw[i][0] >> 16) ^ tag);
                acc |= ((hw[i][1] >> 16) ^ tag);
                acc |= ((hw[i][2] >> 16) ^ tag);
                acc |= ((hw[i][3] >> 16) ^ tag);
            }
            if (__all(acc == 0)) break;
            // cheap canary spin (1 dword/lane) until all producer granules present
            for (;;) {
                unsigned c = load_dword_sc1_wait(cbase);
                if (__all((c >> 16) == tag)) break;
                __builtin_amdgcn_s_sleep(1);
            }
        }
        __builtin_amdgcn_sched_barrier(0);

        // ---- h MFMAs: unpack low16 pairs into bf16x8 fragments ----
        #pragma unroll
        for (int it = 0; it < 8; ++it) {
            u32x4 a = hw[2 * it], b = hw[2 * it + 1];
            u32x4 d;
            d[0] = (a[0] & 0xffffu) | (a[1] << 16);
            d[1] = (a[2] & 0xffffu) | (a[3] << 16);
            d[2] = (b[0] & 0xffffu) | (b[1] << 16);
            d[3] = (b[2] & 0xffffu) | (b[3] << 16);
            bf16x8 af = __builtin_bit_cast(bf16x8, d);
            const __bf16* wp = WhhF + ((size_t)(wave * 8 + it) * 3) * 512 + lane * 8;
            bf16x8 wr = *(const bf16x8*)(wp);
            bf16x8 wz = *(const bf16x8*)(wp + 512);
            bf16x8 wn = *(const bf16x8*)(wp + 1024);
            ar  = __builtin_amdgcn_mfma_f32_16x16x32_bf16(af, wr, ar, 0, 0, 0);
            az  = __builtin_amdgcn_mfma_f32_16x16x32_bf16(af, wz, az, 0, 0, 0);
            anh = __builtin_amdgcn_mfma_f32_16x16x32_bf16(af, wn, anh, 0, 0, 0);
        }

        // D layout: col = lane&15, row = (lane>>4)*4 + j
        #pragma unroll
        for (int j = 0; j < 4; ++j) {
            int row = kgrp * 4 + j;
            prz[wave * 512 + row * 32 + lrow]      = ar[j];
            prz[wave * 512 + row * 32 + 16 + lrow] = az[j];
            pnx[wave * 256 + row * 16 + lrow]      = anx[j];
            pnh[wave * 256 + row * 16 + lrow]      = anh[j];
        }
        __syncthreads();   // SYNC_A: psums from all 4 waves visible

        // ---- gate math: thread (mrow, jcol) owns one output element ----
        {
            float rpre = prz[mrow * 32 + jcol] + prz[512 + mrow * 32 + jcol]
                       + prz[1024 + mrow * 32 + jcol] + prz[1536 + mrow * 32 + jcol] + b_r;
            float zpre = prz[mrow * 32 + 16 + jcol] + prz[512 + mrow * 32 + 16 + jcol]
                       + prz[1024 + mrow * 32 + 16 + jcol] + prz[1536 + mrow * 32 + 16 + jcol] + b_z;
            float ginn = pnx[mrow * 16 + jcol] + pnx[256 + mrow * 16 + jcol]
                       + pnx[512 + mrow * 16 + jcol] + pnx[768 + mrow * 16 + jcol] + b_nx;
            float ghnn = pnh[mrow * 16 + jcol] + pnh[256 + mrow * 16 + jcol]
                       + pnh[512 + mrow * 16 + jcol] + pnh[768 + mrow * 16 + jcol] + b_nh;
            float r = sigmoid_f(rpre);
            float z = sigmoid_f(zpre);
            float n = tanh_f(ginn + r * ghnn);
            float hn = (1.0f - z) * n + z * hp;
            hp = hn;

            // publish h(t+1): tagged word, store-and-forget (no drain, no flag)
            if (t < TT - 1) {
                unsigned hb = (unsigned)__builtin_bit_cast(unsigned short, (__bf16)hn);
                unsigned hword = ((unsigned)(t + 1) << 16) | hb;
                store_dword_sc1(hbuf + (size_t)((t + 1) & 1) * NB * NH + hoff_p, hword);
            }
            // out stores off the sync path
            out[((size_t)(brow + mrow) * TT + t) * NH + hc0 + jcol] = hn;
            if (t == TT - 1)
                out[(size_t)NB * TT * NH + (size_t)(brow + mrow) * NH + hc0 + jcol] = hn;
        }

        __syncthreads();   // SYNC_B: WAR guard for psum LDS reuse
    }
}

extern "C" void kernel_launch(void* const* d_in, const int* in_sizes, int n_in,
                              void* d_out, int out_size, void* d_ws, size_t ws_size,
                              hipStream_t stream) {
    (void)in_sizes; (void)n_in; (void)out_size;
    const float* x    = (const float*)d_in[0];
    const float* W_ih = (const float*)d_in[1];
    const float* W_hh = (const float*)d_in[2];
    const float* b_ih = (const float*)d_in[3];
    const float* b_hh = (const float*)d_in[4];
    float* out = (float*)d_out;

    // ws: 2 parity buffers of tagged h words: 2 * 64 * 1024 * 4B = 512 KB
    unsigned* hbuf = (unsigned*)d_ws;
    const size_t need = (size_t)2 * NB * NH * sizeof(unsigned);
    if (ws_size < need) return;
    hipMemsetAsync(d_ws, 0, need, stream);  // tags=0 (= step-0 tag), h0=0; replay-safe

    const size_t smem_bytes = 163840;
    (void)hipFuncSetAttribute((const void*)gru_kernel,
                              hipFuncAttributeMaxDynamicSharedMemorySize, (int)smem_bytes);
    gru_kernel<<<GRID, NTH, smem_bytes, stream>>>(x, W_ih, W_hh, b_ih, b_hh, out, hbuf);
}

// Round 6
// 3883.986 us; speedup vs baseline: 1.3544x; 1.3544x over previous
//
#include <hip/hip_runtime.h>
#include <hip/hip_bf16.h>

#define NB 64
#define TT 1024
#define ND 512
#define NH 1024
#define GRID 256
#define NTH 256
#define HSLOT ((size_t)NB * NH * 2)   // 128 KB per h slot (bf16)
#define SENT 0xFFFFFFFFu

typedef float f32x4 __attribute__((ext_vector_type(4)));
typedef unsigned u32x4 __attribute__((ext_vector_type(4)));
typedef __bf16 bf16x8 __attribute__((ext_vector_type(8)));

__device__ __forceinline__ float sigmoid_f(float v) { return 1.0f / (1.0f + __expf(-v)); }

__device__ __forceinline__ float tanh_f(float v) {
    float a = fabsf(v);
    float e = __expf(-2.0f * a);
    float t = (1.0f - e) / (1.0f + e);
    return copysignf(t, v);
}

// ---- device-scope (MALL-coherent) accessors: sc1 ----
__device__ __forceinline__ u32x4 load_dwordx4_sc1_off(const void* p, int imm) {
    u32x4 r;
    asm volatile("global_load_dwordx4 %0, %1, off offset:%2 sc1"
                 : "=v"(r) : "v"(p), "i"(imm));
    return r;
}
__device__ __forceinline__ void store_dword_sc1(void* p, unsigned v) {
    asm volatile("global_store_dword %0, %1, off sc1" :: "v"(p), "v"(v) : "memory");
}
__device__ __forceinline__ unsigned load_dword_sc1_wait(const void* p) {
    unsigned v;
    asm volatile("global_load_dword %0, %1, off sc1\n\ts_waitcnt vmcnt(0)"
                 : "=v"(v) : "v"(p) : "memory");
    return v;
}

// LDS weights in exact MFMA B-fragment order (conflict-free ds_read_b128).
// h state: 3 rotating slots of bf16. A slot is sentinel-cleared (0xFFFF pairs)
// one step before its producer rewrites it, so the data validates itself:
// consumer bulk-loads and checks dwords != SENT -> 1 round-trip discovery.
__global__ void __launch_bounds__(NTH) gru_kernel(
    const float* __restrict__ x, const float* __restrict__ W_ih,
    const float* __restrict__ W_hh, const float* __restrict__ b_ih,
    const float* __restrict__ b_hh, float* __restrict__ out,
    unsigned char* __restrict__ hbase)
{
    extern __shared__ char smem[];
    __bf16* WihF = (__bf16*)smem;                  // 49152 B
    __bf16* WhhF = WihF + 4 * 4 * 3 * 64 * 8;      // 98304 B
    float* prz = (float*)(WhhF + 4 * 8 * 3 * 64 * 8);  // [4][16][32] = 8192 B
    float* pnx = prz + 2048;                       // [4][16][16] = 4096 B
    float* pnh = pnx + 1024;                       // [4][16][16] = 4096 B

    const int tid = threadIdx.x;
    const int bg = blockIdx.x >> 6;
    const int cg = blockIdx.x & 63;
    const int brow = bg << 4;
    const int hc0 = cg << 4;

    // ---- one-time: fill fragment-ordered weight LDS (fp32 -> bf16) ----
    for (int s = tid; s < 4 * 4 * 3 * 64; s += NTH) {
        int ln = s & 63, r = s >> 6;
        int g = r % 3, r2 = r / 3;
        int it = r2 & 3, w = r2 >> 2;
        int k = w * 128 + it * 32 + (ln >> 4) * 8;
        int col = ln & 15;
        const float* src = W_ih + (size_t)(g * NH + hc0 + col) * ND + k;
        float4 va = *(const float4*)(src);
        float4 vb = *(const float4*)(src + 4);
        bf16x8 f;
        f[0] = (__bf16)va.x; f[1] = (__bf16)va.y; f[2] = (__bf16)va.z; f[3] = (__bf16)va.w;
        f[4] = (__bf16)vb.x; f[5] = (__bf16)vb.y; f[6] = (__bf16)vb.z; f[7] = (__bf16)vb.w;
        *(bf16x8*)(WihF + (size_t)s * 8) = f;
    }
    for (int s = tid; s < 4 * 8 * 3 * 64; s += NTH) {
        int ln = s & 63, r = s >> 6;
        int g = r % 3, r2 = r / 3;
        int it = r2 & 7, w = r2 >> 3;
        int k = w * 256 + it * 32 + (ln >> 4) * 8;
        int col = ln & 15;
        const float* src = W_hh + (size_t)(g * NH + hc0 + col) * NH + k;
        float4 va = *(const float4*)(src);
        float4 vb = *(const float4*)(src + 4);
        bf16x8 f;
        f[0] = (__bf16)va.x; f[1] = (__bf16)va.y; f[2] = (__bf16)va.z; f[3] = (__bf16)va.w;
        f[4] = (__bf16)vb.x; f[5] = (__bf16)vb.y; f[6] = (__bf16)vb.z; f[7] = (__bf16)vb.w;
        *(bf16x8*)(WhhF + (size_t)s * 8) = f;
    }

    const int jcol = tid & 15;
    const int mrow = tid >> 4;
    const float b_r = b_ih[hc0 + jcol] + b_hh[hc0 + jcol];
    const float b_z = b_ih[NH + hc0 + jcol] + b_hh[NH + hc0 + jcol];
    const float b_nx = b_ih[2 * NH + hc0 + jcol];
    const float b_nh = b_hh[2 * NH + hc0 + jcol];

    __syncthreads();

    const int wave = tid >> 6;
    const int lane = tid & 63;
    const int lrow = lane & 15;
    const int kgrp = lane >> 4;

    // consumer bulk base (bytes): row brow+lrow, k-slice [wave*256 + kgrp*8)
    const size_t coff = ((size_t)(brow + lrow) * NH + wave * 256 + kgrp * 8) * 2;
    // canary: one dword per producer-wave granule of MY slice.
    // lane -> producer block pcg = wave*16 + (lane>>2), producer wave pw = lane&3.
    const size_t cnoff = ((size_t)(brow + 4 * (lane & 3)) * NH
                        + ((size_t)wave * 16 + (lane >> 2)) * 16) * 2;
    // producer element byte offset (dword at even jcol covers jcol, jcol+1)
    const size_t poff = ((size_t)(brow + mrow) * NH + hc0 + jcol) * 2;

    float hp = 0.0f;   // fp32 hidden-state carry in a register

    // prologue: prefetch x fragment for t=0
    f32x4 xa[4], xb[4];
    {
        const float* xr = x + ((size_t)(brow + lrow) * TT + 0) * ND + wave * 128 + kgrp * 8;
        #pragma unroll
        for (int it = 0; it < 4; ++it) {
            xa[it] = *(const f32x4*)(xr + it * 32);
            xb[it] = *(const f32x4*)(xr + it * 32 + 4);
        }
    }

    for (int t = 0; t < TT; ++t) {
        f32x4 ar{}, az{}, anx{}, anh{};

        // ---- x-part from prefetched registers ----
        #pragma unroll
        for (int it = 0; it < 4; ++it) {
            bf16x8 af;
            af[0] = (__bf16)xa[it][0]; af[1] = (__bf16)xa[it][1];
            af[2] = (__bf16)xa[it][2]; af[3] = (__bf16)xa[it][3];
            af[4] = (__bf16)xb[it][0]; af[5] = (__bf16)xb[it][1];
            af[6] = (__bf16)xb[it][2]; af[7] = (__bf16)xb[it][3];
            const __bf16* wp = WihF + ((size_t)(wave * 4 + it) * 3) * 512 + lane * 8;
            bf16x8 wr = *(const bf16x8*)(wp);
            bf16x8 wz = *(const bf16x8*)(wp + 512);
            bf16x8 wn = *(const bf16x8*)(wp + 1024);
            ar  = __builtin_amdgcn_mfma_f32_16x16x32_bf16(af, wr, ar, 0, 0, 0);
            az  = __builtin_amdgcn_mfma_f32_16x16x32_bf16(af, wz, az, 0, 0, 0);
            anx = __builtin_amdgcn_mfma_f32_16x16x32_bf16(af, wn, anx, 0, 0, 0);
        }

        // ---- self-validating bulk h(t) load from slot t%3 (1 RT steady-state) ----
        const unsigned char* hb_r = hbase + (size_t)(t % 3) * HSLOT + coff;
        const unsigned char* cn_r = hbase + (size_t)(t % 3) * HSLOT + cnoff;
        u32x4 hw[8];
        for (;;) {
            hw[0] = load_dwordx4_sc1_off(hb_r,   0);
            hw[1] = load_dwordx4_sc1_off(hb_r,  64);
            hw[2] = load_dwordx4_sc1_off(hb_r, 128);
            hw[3] = load_dwordx4_sc1_off(hb_r, 192);
            hw[4] = load_dwordx4_sc1_off(hb_r, 256);
            hw[5] = load_dwordx4_sc1_off(hb_r, 320);
            hw[6] = load_dwordx4_sc1_off(hb_r, 384);
            hw[7] = load_dwordx4_sc1_off(hb_r, 448);
            asm volatile("s_waitcnt vmcnt(0)" ::: "memory");
            __builtin_amdgcn_sched_barrier(0);
            unsigned bad = 0;
            #pragma unroll
            for (int i = 0; i < 8; ++i) {
                bad |= (hw[i][0] == SENT) | (hw[i][1] == SENT)
                     | (hw[i][2] == SENT) | (hw[i][3] == SENT);
            }
            if (__all(bad == 0)) break;
            // cheap canary spin until all producer granules of my slice landed
            for (;;) {
                unsigned c = load_dword_sc1_wait(cn_r);
                if (__all(c != SENT)) break;
                __builtin_amdgcn_s_sleep(1);
            }
        }
        __builtin_amdgcn_sched_barrier(0);

        // ---- h MFMAs: fragments are the loaded words directly (2B/elem) ----
        #pragma unroll
        for (int it = 0; it < 8; ++it) {
            bf16x8 af = __builtin_bit_cast(bf16x8, hw[it]);
            const __bf16* wp = WhhF + ((size_t)(wave * 8 + it) * 3) * 512 + lane * 8;
            bf16x8 wr = *(const bf16x8*)(wp);
            bf16x8 wz = *(const bf16x8*)(wp + 512);
            bf16x8 wn = *(const bf16x8*)(wp + 1024);
            ar  = __builtin_amdgcn_mfma_f32_16x16x32_bf16(af, wr, ar, 0, 0, 0);
            az  = __builtin_amdgcn_mfma_f32_16x16x32_bf16(af, wz, az, 0, 0, 0);
            anh = __builtin_amdgcn_mfma_f32_16x16x32_bf16(af, wn, anh, 0, 0, 0);
        }

        // D layout: col = lane&15, row = (lane>>4)*4 + j
        #pragma unroll
        for (int j = 0; j < 4; ++j) {
            int row = kgrp * 4 + j;
            prz[wave * 512 + row * 32 + lrow]      = ar[j];
            prz[wave * 512 + row * 32 + 16 + lrow] = az[j];
            pnx[wave * 256 + row * 16 + lrow]      = anx[j];
            pnh[wave * 256 + row * 16 + lrow]      = anh[j];
        }
        __syncthreads();   // SYNC_A: psums visible AND all 4 waves validated h(t)
                           // -> all 64 blocks are past consuming h(t-1): clears safe.

        // ---- sentinel-clear slot (t+2)%3 (holds dead h(t-1)); then x-prefetch ----
        if (t <= TT - 3 && (jcol & 1) == 0)
            store_dword_sc1(hbase + (size_t)((t + 2) % 3) * HSLOT + poff, SENT);
        if (t + 1 < TT) {   // issued AFTER clears: vmcnt(8) below retires the clear only
            const float* xn = x + ((size_t)(brow + lrow) * TT + (t + 1)) * ND
                            + wave * 128 + kgrp * 8;
            #pragma unroll
            for (int it = 0; it < 4; ++it) {
                xa[it] = *(const f32x4*)(xn + it * 32);
                xb[it] = *(const f32x4*)(xn + it * 32 + 4);
            }
        }

        // ---- gate math: thread (mrow, jcol) owns one output element ----
        {
            float rpre = prz[mrow * 32 + jcol] + prz[512 + mrow * 32 + jcol]
                       + prz[1024 + mrow * 32 + jcol] + prz[1536 + mrow * 32 + jcol] + b_r;
            float zpre = prz[mrow * 32 + 16 + jcol] + prz[512 + mrow * 32 + 16 + jcol]
                       + prz[1024 + mrow * 32 + 16 + jcol] + prz[1536 + mrow * 32 + 16 + jcol] + b_z;
            float ginn = pnx[mrow * 16 + jcol] + pnx[256 + mrow * 16 + jcol]
                       + pnx[512 + mrow * 16 + jcol] + pnx[768 + mrow * 16 + jcol] + b_nx;
            float ghnn = pnh[mrow * 16 + jcol] + pnh[256 + mrow * 16 + jcol]
                       + pnh[512 + mrow * 16 + jcol] + pnh[768 + mrow * 16 + jcol] + b_nh;
            float r = sigmoid_f(rpre);
            float z = sigmoid_f(zpre);
            float n = tanh_f(ginn + r * ghnn);
            float hn = (1.0f - z) * n + z * hp;
            hp = hn;

            // publish h(t+1) as dword pairs: store-atom == validation-atom
            unsigned hb16 = (unsigned)__builtin_bit_cast(unsigned short, (__bf16)hn);
            unsigned nb16 = (unsigned)__shfl_xor((int)hb16, 1);
            if (t < TT - 1) {
                // counted wait: retires this step's clear (older than the 8 x loads),
                // never stalls on the x prefetch. In-order vmcnt decrement.
                asm volatile("s_waitcnt vmcnt(8)" ::: "memory");
                if ((jcol & 1) == 0)
                    store_dword_sc1(hbase + (size_t)((t + 1) % 3) * HSLOT + poff,
                                    hb16 | (nb16 << 16));
            }
            // out stores off the sync path
            out[((size_t)(brow + mrow) * TT + t) * NH + hc0 + jcol] = hn;
            if (t == TT - 1)
                out[(size_t)NB * TT * NH + (size_t)(brow + mrow) * NH + hc0 + jcol] = hn;
        }

        __syncthreads();   // SYNC_B: WAR guard for psum LDS reuse
    }
}

extern "C" void kernel_launch(void* const* d_in, const int* in_sizes, int n_in,
                              void* d_out, int out_size, void* d_ws, size_t ws_size,
                              hipStream_t stream) {
    (void)in_sizes; (void)n_in; (void)out_size;
    const float* x    = (const float*)d_in[0];
    const float* W_ih = (const float*)d_in[1];
    const float* W_hh = (const float*)d_in[2];
    const float* b_ih = (const float*)d_in[3];
    const float* b_hh = (const float*)d_in[4];
    float* out = (float*)d_out;

    // ws: 3 rotating h slots (bf16), 3 * 128 KB.
    unsigned char* hbase = (unsigned char*)d_ws;
    if (ws_size < 3 * HSLOT) return;
    // slot0 = h(0) = 0.0 (valid, non-sentinel); slots 1,2 = sentinel 0xFFFF...
    hipMemsetAsync(hbase, 0x00, HSLOT, stream);
    hipMemsetAsync(hbase + HSLOT, 0xFF, 2 * HSLOT, stream);

    const size_t smem_bytes = 163840;
    (void)hipFuncSetAttribute((const void*)gru_kernel,
                              hipFuncAttributeMaxDynamicSharedMemorySize, (int)smem_bytes);
    gru_kernel<<<GRID, NTH, smem_bytes, stream>>>(x, W_ih, W_hh, b_ih, b_hh, out, hbase);
}